// Round 14
// baseline (86.557 us; speedup 1.0000x reference)
//
#include <hip/hip_runtime.h>
#include <math.h>

#define EPS 1e-6f

constexpr int B_ = 32;
constexpr int T_ = 8192;
constexpr int F_ = 128;
constexpr int FH = F_ / 2;        // 64 float2 feature-pairs per timestep
constexpr int C_ = 512;           // main steps per block
constexpr int W_ = 512;           // warmup window: a^512 ~ 2.4e-6
constexpr int SLOTS = 8;          // 8 slots x 64 lanes = 512 threads
constexpr int SEG = C_ / SLOTS;   // 64 steps per slot segment
constexpr int GPB = T_ / C_;      // 16 blocks per batch row
constexpr int NBLK = B_ * GPB;    // 512 blocks = 2/CU, 16 waves/CU

// fast pow for strictly-positive base
__device__ __forceinline__ float fpow(float b, float e) {
    return exp2f(e * __log2f(b));
}

template<bool RHALF>
__device__ __forceinline__ float yval(float xv, float cc, float na, float d,
                                      float r, float dr)
{
    const float p = exp2f(na * __log2f(EPS + cc));   // (EPS+E)^-alpha
    const float v = fmaf(xv, p, d);                   // u + delta
    const float t = RHALF ? sqrtf(v) : exp2f(r * __log2f(v));
    return t - dr;
}

template<bool RHALF>
__device__ __forceinline__ void phaseC(
    const float2* __restrict__ xrow, float2* __restrict__ yrow, int tm,
    float& c0, float& c1,
    float s0, float s1, float a0, float a1,
    float na0, float na1, float d0, float d1,
    float r0, float r1, float dr0, float dr1)
{
    #pragma unroll 2
    for (int i = 0; i < SEG; i += 4) {
        const float2 v0 = xrow[(size_t)(tm + i + 0) * FH];
        const float2 v1 = xrow[(size_t)(tm + i + 1) * FH];
        const float2 v2 = xrow[(size_t)(tm + i + 2) * FH];
        const float2 v3 = xrow[(size_t)(tm + i + 3) * FH];

        float2 yv0, yv1, yv2, yv3;

        c0 = fmaf(a0, c0, s0 * v0.x);  c1 = fmaf(a1, c1, s1 * v0.y);
        yv0.x = yval<RHALF>(v0.x, c0, na0, d0, r0, dr0);
        yv0.y = yval<RHALF>(v0.y, c1, na1, d1, r1, dr1);

        c0 = fmaf(a0, c0, s0 * v1.x);  c1 = fmaf(a1, c1, s1 * v1.y);
        yv1.x = yval<RHALF>(v1.x, c0, na0, d0, r0, dr0);
        yv1.y = yval<RHALF>(v1.y, c1, na1, d1, r1, dr1);

        c0 = fmaf(a0, c0, s0 * v2.x);  c1 = fmaf(a1, c1, s1 * v2.y);
        yv2.x = yval<RHALF>(v2.x, c0, na0, d0, r0, dr0);
        yv2.y = yval<RHALF>(v2.y, c1, na1, d1, r1, dr1);

        c0 = fmaf(a0, c0, s0 * v3.x);  c1 = fmaf(a1, c1, s1 * v3.y);
        yv3.x = yval<RHALF>(v3.x, c0, na0, d0, r0, dr0);
        yv3.y = yval<RHALF>(v3.y, c1, na1, d1, r1, dr1);

        yrow[(size_t)(tm + i + 0) * FH] = yv0;
        yrow[(size_t)(tm + i + 1) * FH] = yv1;
        yrow[(size_t)(tm + i + 2) * FH] = yv2;
        yrow[(size_t)(tm + i + 3) * FH] = yv3;
    }
}

__global__ __launch_bounds__(512, 4) void pcen_fused1(
    const float2* __restrict__ x2,
    const float2* __restrict__ state2,
    const float*  __restrict__ log_s,
    const float*  __restrict__ log_alpha,
    const float*  __restrict__ log_delta,
    const float*  __restrict__ log_r,
    float2* __restrict__ y2,
    float2* __restrict__ ns2)
{
    __shared__ float2 Sw[SLOTS][FH];   // warmup-segment partial sums
    __shared__ float2 Sm[SLOTS][FH];   // main-segment partial sums

    const int lane = threadIdx.x & 63;   // feature pair
    const int slot = threadIdx.x >> 6;   // 0..7 (wave-uniform)
    const int g    = blockIdx.x % GPB;
    const int b    = blockIdx.x / GPB;
    const int T0   = g * C_;

    const float2 lsv = reinterpret_cast<const float2*>(log_s)[lane];
    const float s0 = expf(lsv.x), s1 = expf(lsv.y);
    const float a0 = 1.f - s0,   a1 = 1.f - s1;

    const float2* xrow = x2 + (size_t)b * T_ * FH + lane;

    const int tw = T0 - W_ + SEG * slot;   // warmup segment start
    const int tm = T0 + SEG * slot;        // main segment start

    // ---- phase A: two zero-carry local sums (independent chains, batch-4) ----
    float w0 = 0.f, w1 = 0.f, m0 = 0.f, m1 = 0.f;
    if (g > 0) {
        #pragma unroll 2
        for (int i = 0; i < SEG; i += 4) {
            const float2 u0 = xrow[(size_t)(tw + i + 0) * FH];
            const float2 u1 = xrow[(size_t)(tw + i + 1) * FH];
            const float2 u2 = xrow[(size_t)(tw + i + 2) * FH];
            const float2 u3 = xrow[(size_t)(tw + i + 3) * FH];
            const float2 v0 = xrow[(size_t)(tm + i + 0) * FH];
            const float2 v1 = xrow[(size_t)(tm + i + 1) * FH];
            const float2 v2 = xrow[(size_t)(tm + i + 2) * FH];
            const float2 v3 = xrow[(size_t)(tm + i + 3) * FH];

            w0 = fmaf(a0, w0, s0 * u0.x);  w1 = fmaf(a1, w1, s1 * u0.y);
            m0 = fmaf(a0, m0, s0 * v0.x);  m1 = fmaf(a1, m1, s1 * v0.y);
            w0 = fmaf(a0, w0, s0 * u1.x);  w1 = fmaf(a1, w1, s1 * u1.y);
            m0 = fmaf(a0, m0, s0 * v1.x);  m1 = fmaf(a1, m1, s1 * v1.y);
            w0 = fmaf(a0, w0, s0 * u2.x);  w1 = fmaf(a1, w1, s1 * u2.y);
            m0 = fmaf(a0, m0, s0 * v2.x);  m1 = fmaf(a1, m1, s1 * v2.y);
            w0 = fmaf(a0, w0, s0 * u3.x);  w1 = fmaf(a1, w1, s1 * u3.y);
            m0 = fmaf(a0, m0, s0 * v3.x);  m1 = fmaf(a1, m1, s1 * v3.y);
        }
    } else {
        #pragma unroll 2
        for (int i = 0; i < SEG; i += 4) {
            const float2 v0 = xrow[(size_t)(tm + i + 0) * FH];
            const float2 v1 = xrow[(size_t)(tm + i + 1) * FH];
            const float2 v2 = xrow[(size_t)(tm + i + 2) * FH];
            const float2 v3 = xrow[(size_t)(tm + i + 3) * FH];
            m0 = fmaf(a0, m0, s0 * v0.x);  m1 = fmaf(a1, m1, s1 * v0.y);
            m0 = fmaf(a0, m0, s0 * v1.x);  m1 = fmaf(a1, m1, s1 * v1.y);
            m0 = fmaf(a0, m0, s0 * v2.x);  m1 = fmaf(a1, m1, s1 * v2.y);
            m0 = fmaf(a0, m0, s0 * v3.x);  m1 = fmaf(a1, m1, s1 * v3.y);
        }
    }
    Sw[slot][lane] = make_float2(w0, w1);
    Sm[slot][lane] = make_float2(m0, m1);
    __syncthreads();

    // ---- A64 = a^SEG by 6 squarings ----
    float A640 = a0, A641 = a1;
    #pragma unroll
    for (int q = 0; q < 6; ++q) { A640 *= A640; A641 *= A641; }

    // ---- phase B: assemble carry at main-segment start ----
    // c_slot = sum_k A64^(7-k+slot) * Sw[k] + sum_{k<slot} A64^(slot-1-k) * Sm[k]
    //          (+ state term: g==0 exact, g==1 with coef A64^(slot+8) = a^(512+64*slot))
    float c0 = 0.f, c1 = 0.f;
    float cw0 = 1.f, cw1 = 1.f;
    for (int m = 0; m < slot; ++m) { cw0 *= A640; cw1 *= A641; }   // A64^slot
    if (g > 0) {
        #pragma unroll
        for (int k = SLOTS - 1; k >= 0; --k) {
            const float2 Sv = Sw[k][lane];
            c0 = fmaf(cw0, Sv.x, c0);
            c1 = fmaf(cw1, Sv.y, c1);
            cw0 *= A640; cw1 *= A641;
        }
    }
    if (g <= 1) {
        const float2 st = state2[(size_t)b * FH + lane];
        c0 = fmaf(cw0, st.x, c0);
        c1 = fmaf(cw1, st.y, c1);
    }
    {
        float cm0 = 1.f, cm1 = 1.f;
        for (int k = slot - 1; k >= 0; --k) {
            const float2 Sv = Sm[k][lane];
            c0 = fmaf(cm0, Sv.x, c0);
            c1 = fmaf(cm1, Sv.y, c1);
            cm0 *= A640; cm1 *= A641;
        }
    }

    // ---- phase C: recurrence + y over the (cache-hot) main segment ----
    const float2 lav = reinterpret_cast<const float2*>(log_alpha)[lane];
    const float2 ldv = reinterpret_cast<const float2*>(log_delta)[lane];
    const float2 lrv = reinterpret_cast<const float2*>(log_r)[lane];
    const float na0 = -expf(lav.x), na1 = -expf(lav.y);
    const float d0 = expf(ldv.x),  d1 = expf(ldv.y);
    const float r0 = expf(lrv.x),  r1 = expf(lrv.y);

    const bool allhalf = __all((r0 == 0.5f) && (r1 == 0.5f));
    const float dr0 = allhalf ? sqrtf(d0) : fpow(d0, r0);
    const float dr1 = allhalf ? sqrtf(d1) : fpow(d1, r1);

    float2* yrow = y2 + (size_t)b * T_ * FH + lane;

    if (allhalf) {
        phaseC<true >(xrow, yrow, tm, c0, c1, s0, s1, a0, a1,
                      na0, na1, d0, d1, r0, r1, dr0, dr1);
    } else {
        phaseC<false>(xrow, yrow, tm, c0, c1, s0, s1, a0, a1,
                      na0, na1, d0, d1, r0, r1, dr0, dr1);
    }

    // final state: last block's last slot ends exactly at t = T
    if (g == GPB - 1 && slot == SLOTS - 1) {
        ns2[(size_t)b * FH + lane] = make_float2(c0, c1);
    }
}

extern "C" void kernel_launch(void* const* d_in, const int* in_sizes, int n_in,
                              void* d_out, int out_size, void* d_ws, size_t ws_size,
                              hipStream_t stream)
{
    const float* x         = (const float*)d_in[0];
    const float* state     = (const float*)d_in[1];
    const float* log_s     = (const float*)d_in[2];
    const float* log_alpha = (const float*)d_in[3];
    const float* log_delta = (const float*)d_in[4];
    const float* log_r     = (const float*)d_in[5];

    float* y         = (float*)d_out;
    float* new_state = y + (size_t)B_ * T_ * F_;

    pcen_fused1<<<dim3(NBLK), dim3(512), 0, stream>>>(
        (const float2*)x, (const float2*)state,
        log_s, log_alpha, log_delta, log_r,
        (float2*)y, (float2*)new_state);
}

// Round 15
// 75.412 us; speedup vs baseline: 1.1478x; 1.1478x over previous
//
#include <hip/hip_runtime.h>
#include <math.h>

#define EPS 1e-6f

constexpr int B_ = 32;
constexpr int T_ = 8192;
constexpr int F_ = 128;
constexpr int FG = F_ / 4;    // 32 float4 feature-groups per row
constexpr int FH = F_ / 2;    // 64 float2 feature-pairs per row

// fast pow for strictly-positive base
__device__ __forceinline__ float fpow(float b, float e) {
    return exp2f(e * __log2f(b));
}

// -------- pass 1 (unchanged): per-chunk local sums --------
template<int NC>
__global__ __launch_bounds__(256) void pcen_pass1(
    const float4* __restrict__ x4,
    const float*  __restrict__ log_s,
    float4* __restrict__ S4)
{
    constexpr int L = T_ / NC;
    const int fg    = threadIdx.x & 31;
    const int slot  = threadIdx.x >> 5;              // 0..7
    const int cb    = blockIdx.x % (NC / 8);
    const int b     = blockIdx.x / (NC / 8);
    const int chunk = cb * 8 + slot;

    const float4 lsv = reinterpret_cast<const float4*>(log_s)[fg];
    const float s0 = expf(lsv.x), s1 = expf(lsv.y), s2 = expf(lsv.z), s3 = expf(lsv.w);
    const float a0 = 1.f - s0,   a1 = 1.f - s1,    a2 = 1.f - s2,    a3 = 1.f - s3;

    const float4* xp = x4 + ((size_t)b * T_ + (size_t)chunk * L) * FG + fg;

    float c0 = 0.f, c1 = 0.f, c2 = 0.f, c3 = 0.f;
    #pragma unroll
    for (int i = 0; i < L; ++i) {
        const float4 xv = xp[(size_t)i * FG];
        c0 = fmaf(a0, c0, s0 * xv.x);
        c1 = fmaf(a1, c1, s1 * xv.y);
        c2 = fmaf(a2, c2, s2 * xv.z);
        c3 = fmaf(a3, c3, s3 * xv.w);
    }
    S4[((size_t)b * NC + chunk) * FG + fg] = make_float4(c0, c1, c2, c3);
}

// -------- pass 3: windowed-lookback carry + recurrence + y --------
// Replaces pass2 entirely: each thread rebuilds its chunk's carry from the
// S buffer, walking backward until the decay coefficient is < 1e-7.
template<int NC>
__global__ __launch_bounds__(256) void pcen_pass3(
    const float2* __restrict__ x2,
    const float2* __restrict__ state2,
    const float*  __restrict__ log_s,
    const float*  __restrict__ log_alpha,
    const float*  __restrict__ log_delta,
    const float*  __restrict__ log_r,
    const float2* __restrict__ S2,       // [B][NC][FH] local sums from pass1
    float2* __restrict__ y2,
    float2* __restrict__ ns2)
{
    constexpr int L = T_ / NC;            // 32
    const int lane  = threadIdx.x & 63;   // feature pair 0..63
    const int slot  = threadIdx.x >> 6;   // 0..3 chunk slot
    const int cb    = blockIdx.x % (NC / 4);
    const int b     = blockIdx.x / (NC / 4);
    const int chunk = cb * 4 + slot;

    const float2 lsv = reinterpret_cast<const float2*>(log_s)[lane];
    const float s0 = expf(lsv.x), s1 = expf(lsv.y);
    const float a0 = 1.f - s0,   a1 = 1.f - s1;
    const float aL0 = fpow(a0, (float)L);
    const float aL1 = fpow(a1, (float)L);

    // ---- windowed lookback: carry into this chunk ----
    // c = sum_{k<chunk} aL^(chunk-1-k) * S[k]  (+ aL^chunk * state)
    // truncated where the coefficient falls below 1e-7 (generic in log_s).
    float c0 = 0.f, c1 = 0.f;
    {
        float coef0 = 1.f, coef1 = 1.f;
        int k = chunk - 1;
        for (; k >= 0; --k) {
            if (coef0 < 1e-7f && coef1 < 1e-7f) break;
            const float2 Sv = S2[((size_t)b * NC + k) * FH + lane];
            c0 = fmaf(coef0, Sv.x, c0);
            c1 = fmaf(coef1, Sv.y, c1);
            coef0 *= aL0;
            coef1 *= aL1;
        }
        if (k < 0) {   // reached t=0 with live coefficient: include true state
            const float2 st = state2[(size_t)b * FH + lane];
            c0 = fmaf(coef0, st.x, c0);
            c1 = fmaf(coef1, st.y, c1);
        }
    }

    // ---- y parameters ----
    const float2 lav = reinterpret_cast<const float2*>(log_alpha)[lane];
    const float2 ldv = reinterpret_cast<const float2*>(log_delta)[lane];
    const float2 lrv = reinterpret_cast<const float2*>(log_r)[lane];
    const float na0 = -expf(lav.x), na1 = -expf(lav.y);
    const float d0 = expf(ldv.x),  d1 = expf(ldv.y);
    const float r0 = expf(lrv.x),  r1 = expf(lrv.y);
    const float dr0 = fpow(d0, r0), dr1 = fpow(d1, r1);

    const size_t base = ((size_t)b * T_ + (size_t)chunk * L) * FH + lane;
    const float2* xp = x2 + base;
    float2*       yp = y2 + base;

    float2 c; c.x = c0; c.y = c1;

    #pragma unroll
    for (int i = 0; i < L; i += 4) {
        float2 xv0 = xp[(size_t)(i + 0) * FH];
        float2 xv1 = xp[(size_t)(i + 1) * FH];
        float2 xv2 = xp[(size_t)(i + 2) * FH];
        float2 xv3 = xp[(size_t)(i + 3) * FH];

        float2 yv0, yv1, yv2, yv3;

        c.x = fmaf(a0, c.x, s0 * xv0.x);
        c.y = fmaf(a1, c.y, s1 * xv0.y);
        yv0.x = exp2f(r0 * __log2f(fmaf(xv0.x, exp2f(na0 * __log2f(EPS + c.x)), d0))) - dr0;
        yv0.y = exp2f(r1 * __log2f(fmaf(xv0.y, exp2f(na1 * __log2f(EPS + c.y)), d1))) - dr1;

        c.x = fmaf(a0, c.x, s0 * xv1.x);
        c.y = fmaf(a1, c.y, s1 * xv1.y);
        yv1.x = exp2f(r0 * __log2f(fmaf(xv1.x, exp2f(na0 * __log2f(EPS + c.x)), d0))) - dr0;
        yv1.y = exp2f(r1 * __log2f(fmaf(xv1.y, exp2f(na1 * __log2f(EPS + c.y)), d1))) - dr1;

        c.x = fmaf(a0, c.x, s0 * xv2.x);
        c.y = fmaf(a1, c.y, s1 * xv2.y);
        yv2.x = exp2f(r0 * __log2f(fmaf(xv2.x, exp2f(na0 * __log2f(EPS + c.x)), d0))) - dr0;
        yv2.y = exp2f(r1 * __log2f(fmaf(xv2.y, exp2f(na1 * __log2f(EPS + c.y)), d1))) - dr1;

        c.x = fmaf(a0, c.x, s0 * xv3.x);
        c.y = fmaf(a1, c.y, s1 * xv3.y);
        yv3.x = exp2f(r0 * __log2f(fmaf(xv3.x, exp2f(na0 * __log2f(EPS + c.x)), d0))) - dr0;
        yv3.y = exp2f(r1 * __log2f(fmaf(xv3.y, exp2f(na1 * __log2f(EPS + c.y)), d1))) - dr1;

        yp[(size_t)(i + 0) * FH] = yv0;
        yp[(size_t)(i + 1) * FH] = yv1;
        yp[(size_t)(i + 2) * FH] = yv2;
        yp[(size_t)(i + 3) * FH] = yv3;
    }

    // final state: last chunk's stepwise carry IS state at t=T (exact path)
    if (chunk == NC - 1) {
        ns2[(size_t)b * FH + lane] = c;
    }
}

template<int NC>
static void launch_all(const float* x, const float* state,
                       const float* log_s, const float* log_alpha,
                       const float* log_delta, const float* log_r,
                       float* y, float* new_state, float* ws, hipStream_t stream)
{
    const float4* x4 = (const float4*)x;
    float4* S4       = (float4*)ws;      // B*NC*FG float4

    pcen_pass1<NC><<<dim3(B_ * (NC / 8)), dim3(256), 0, stream>>>(x4, log_s, S4);
    pcen_pass3<NC><<<dim3(B_ * (NC / 4)), dim3(256), 0, stream>>>(
        (const float2*)x, (const float2*)state,
        log_s, log_alpha, log_delta, log_r,
        (const float2*)S4, (float2*)y, (float2*)new_state);
}

extern "C" void kernel_launch(void* const* d_in, const int* in_sizes, int n_in,
                              void* d_out, int out_size, void* d_ws, size_t ws_size,
                              hipStream_t stream)
{
    const float* x         = (const float*)d_in[0];
    const float* state     = (const float*)d_in[1];
    const float* log_s     = (const float*)d_in[2];
    const float* log_alpha = (const float*)d_in[3];
    const float* log_delta = (const float*)d_in[4];
    const float* log_r     = (const float*)d_in[5];

    float* y         = (float*)d_out;
    float* new_state = y + (size_t)B_ * T_ * F_;

    // workspace need: 1 buffer of B*NC*F floats
    const size_t need256 = (size_t)B_ * 256 * F_ * sizeof(float);   // 4 MB
    const size_t need128 = (size_t)B_ * 128 * F_ * sizeof(float);   // 2 MB
    if (ws_size >= need256) {
        launch_all<256>(x, state, log_s, log_alpha, log_delta, log_r,
                        y, new_state, (float*)d_ws, stream);
    } else if (ws_size >= need128) {
        launch_all<128>(x, state, log_s, log_alpha, log_delta, log_r,
                        y, new_state, (float*)d_ws, stream);
    } else {
        launch_all<64>(x, state, log_s, log_alpha, log_delta, log_r,
                       y, new_state, (float*)d_ws, stream);
    }
}

// Round 16
// 74.925 us; speedup vs baseline: 1.1552x; 1.0065x over previous
//
#include <hip/hip_runtime.h>
#include <math.h>

#define EPS 1e-6f

constexpr int B_ = 32;
constexpr int T_ = 8192;
constexpr int F_ = 128;
constexpr int FG = F_ / 4;    // 32 float4 feature-groups per row
constexpr int FH = F_ / 2;    // 64 float2 feature-pairs per row

// fast pow for strictly-positive base
__device__ __forceinline__ float fpow(float b, float e) {
    return exp2f(e * __log2f(b));
}

// -------- pass 1 (unchanged): per-chunk local sums --------
template<int NC>
__global__ __launch_bounds__(256) void pcen_pass1(
    const float4* __restrict__ x4,
    const float*  __restrict__ log_s,
    float4* __restrict__ S4)
{
    constexpr int L = T_ / NC;
    const int fg    = threadIdx.x & 31;
    const int slot  = threadIdx.x >> 5;              // 0..7
    const int cb    = blockIdx.x % (NC / 8);
    const int b     = blockIdx.x / (NC / 8);
    const int chunk = cb * 8 + slot;

    const float4 lsv = reinterpret_cast<const float4*>(log_s)[fg];
    const float s0 = expf(lsv.x), s1 = expf(lsv.y), s2 = expf(lsv.z), s3 = expf(lsv.w);
    const float a0 = 1.f - s0,   a1 = 1.f - s1,    a2 = 1.f - s2,    a3 = 1.f - s3;

    const float4* xp = x4 + ((size_t)b * T_ + (size_t)chunk * L) * FG + fg;

    float c0 = 0.f, c1 = 0.f, c2 = 0.f, c3 = 0.f;
    #pragma unroll
    for (int i = 0; i < L; ++i) {
        const float4 xv = xp[(size_t)i * FG];
        c0 = fmaf(a0, c0, s0 * xv.x);
        c1 = fmaf(a1, c1, s1 * xv.y);
        c2 = fmaf(a2, c2, s2 * xv.z);
        c3 = fmaf(a3, c3, s3 * xv.w);
    }
    S4[((size_t)b * NC + chunk) * FG + fg] = make_float4(c0, c1, c2, c3);
}

// -------- pass 3: windowed-lookback carry + recurrence + y (batch-8) --------
template<int NC>
__global__ __launch_bounds__(256) void pcen_pass3(
    const float2* __restrict__ x2,
    const float2* __restrict__ state2,
    const float*  __restrict__ log_s,
    const float*  __restrict__ log_alpha,
    const float*  __restrict__ log_delta,
    const float*  __restrict__ log_r,
    const float2* __restrict__ S2,       // [B][NC][FH] local sums from pass1
    float2* __restrict__ y2,
    float2* __restrict__ ns2)
{
    constexpr int L = T_ / NC;            // 32
    const int lane  = threadIdx.x & 63;   // feature pair 0..63
    const int slot  = threadIdx.x >> 6;   // 0..3 chunk slot
    const int cb    = blockIdx.x % (NC / 4);
    const int b     = blockIdx.x / (NC / 4);
    const int chunk = cb * 4 + slot;

    const float2 lsv = reinterpret_cast<const float2*>(log_s)[lane];
    const float s0 = expf(lsv.x), s1 = expf(lsv.y);
    const float a0 = 1.f - s0,   a1 = 1.f - s1;
    const float aL0 = fpow(a0, (float)L);
    const float aL1 = fpow(a1, (float)L);

    // ---- windowed lookback: carry into this chunk ----
    float c0 = 0.f, c1 = 0.f;
    {
        float coef0 = 1.f, coef1 = 1.f;
        int k = chunk - 1;
        for (; k >= 0; --k) {
            if (coef0 < 1e-7f && coef1 < 1e-7f) break;
            const float2 Sv = S2[((size_t)b * NC + k) * FH + lane];
            c0 = fmaf(coef0, Sv.x, c0);
            c1 = fmaf(coef1, Sv.y, c1);
            coef0 *= aL0;
            coef1 *= aL1;
        }
        if (k < 0) {   // reached t=0 with live coefficient: include true state
            const float2 st = state2[(size_t)b * FH + lane];
            c0 = fmaf(coef0, st.x, c0);
            c1 = fmaf(coef1, st.y, c1);
        }
    }

    // ---- y parameters ----
    const float2 lav = reinterpret_cast<const float2*>(log_alpha)[lane];
    const float2 ldv = reinterpret_cast<const float2*>(log_delta)[lane];
    const float2 lrv = reinterpret_cast<const float2*>(log_r)[lane];
    const float na0 = -expf(lav.x), na1 = -expf(lav.y);
    const float d0 = expf(ldv.x),  d1 = expf(ldv.y);
    const float r0 = expf(lrv.x),  r1 = expf(lrv.y);
    const float dr0 = fpow(d0, r0), dr1 = fpow(d1, r1);

    const size_t base = ((size_t)b * T_ + (size_t)chunk * L) * FH + lane;
    const float2* xp = x2 + base;
    float2*       yp = y2 + base;

    float2 c; c.x = c0; c.y = c1;

    // batch-8: 8 independent 8B loads in flight, 8 independent y-chains,
    // then one 8-store burst. All indices compile-time after unroll.
    #pragma unroll
    for (int i = 0; i < L; i += 8) {
        float2 xv[8];
        #pragma unroll
        for (int j = 0; j < 8; ++j) xv[j] = xp[(size_t)(i + j) * FH];

        float2 yv[8];
        #pragma unroll
        for (int j = 0; j < 8; ++j) {
            c.x = fmaf(a0, c.x, s0 * xv[j].x);
            c.y = fmaf(a1, c.y, s1 * xv[j].y);
            yv[j].x = exp2f(r0 * __log2f(fmaf(xv[j].x, exp2f(na0 * __log2f(EPS + c.x)), d0))) - dr0;
            yv[j].y = exp2f(r1 * __log2f(fmaf(xv[j].y, exp2f(na1 * __log2f(EPS + c.y)), d1))) - dr1;
        }

        #pragma unroll
        for (int j = 0; j < 8; ++j) yp[(size_t)(i + j) * FH] = yv[j];
    }

    // final state: last chunk's stepwise carry IS state at t=T (exact path)
    if (chunk == NC - 1) {
        ns2[(size_t)b * FH + lane] = c;
    }
}

template<int NC>
static void launch_all(const float* x, const float* state,
                       const float* log_s, const float* log_alpha,
                       const float* log_delta, const float* log_r,
                       float* y, float* new_state, float* ws, hipStream_t stream)
{
    const float4* x4 = (const float4*)x;
    float4* S4       = (float4*)ws;      // B*NC*FG float4

    pcen_pass1<NC><<<dim3(B_ * (NC / 8)), dim3(256), 0, stream>>>(x4, log_s, S4);
    pcen_pass3<NC><<<dim3(B_ * (NC / 4)), dim3(256), 0, stream>>>(
        (const float2*)x, (const float2*)state,
        log_s, log_alpha, log_delta, log_r,
        (const float2*)S4, (float2*)y, (float2*)new_state);
}

extern "C" void kernel_launch(void* const* d_in, const int* in_sizes, int n_in,
                              void* d_out, int out_size, void* d_ws, size_t ws_size,
                              hipStream_t stream)
{
    const float* x         = (const float*)d_in[0];
    const float* state     = (const float*)d_in[1];
    const float* log_s     = (const float*)d_in[2];
    const float* log_alpha = (const float*)d_in[3];
    const float* log_delta = (const float*)d_in[4];
    const float* log_r     = (const float*)d_in[5];

    float* y         = (float*)d_out;
    float* new_state = y + (size_t)B_ * T_ * F_;

    // workspace need: 1 buffer of B*NC*F floats
    const size_t need256 = (size_t)B_ * 256 * F_ * sizeof(float);   // 4 MB
    const size_t need128 = (size_t)B_ * 128 * F_ * sizeof(float);   // 2 MB
    if (ws_size >= need256) {
        launch_all<256>(x, state, log_s, log_alpha, log_delta, log_r,
                        y, new_state, (float*)d_ws, stream);
    } else if (ws_size >= need128) {
        launch_all<128>(x, state, log_s, log_alpha, log_delta, log_r,
                        y, new_state, (float*)d_ws, stream);
    } else {
        launch_all<64>(x, state, log_s, log_alpha, log_delta, log_r,
                       y, new_state, (float*)d_ws, stream);
    }
}